// Round 8
// baseline (825.914 us; speedup 1.0000x reference)
//
#include <hip/hip_runtime.h>
#include <hip/hip_bf16.h>

// N=65536 points, H=256, 4 hidden layers, ReLU MLP -> (psi,p).
// ReLU => piecewise linear => Hessians vanish; f = p_x, g = p_y (RHO=1).
// Pipeline:
//   1) fp32 forward replicating np/BLAS arithmetic BIT-EXACTLY
//      (k-ascending single-acc fmaf chain, bias after, mask = a>0).
//      v8: NO LDS h — h ping-pongs through two block-private GLOBAL
//      buffers in [col][pt] layout (coalesced both ways); W via scalar
//      loads. LDS 2.3KB -> 32 waves/CU so the SMEM lgkmcnt(0) drains are
//      hidden by TLP (v6/v7 stuck at 56% VALUBusy, 39% occupancy).
//   2) ONE fused tangent kernel (v7): T1 init from masks+Win, 4 MFMA
//      layers with mask-gated f16 LDS roundtrip, fused finalize.
// Workspace: bufA 64MB | bufB 64MB | masks 5x2MB | Wt 512KB

#define NPTS 65536
#define HDIM 256

typedef _Float16 half8_t __attribute__((ext_vector_type(8)));
typedef _Float16 half4_t __attribute__((ext_vector_type(4)));
typedef float floatx4 __attribute__((ext_vector_type(4)));

// ---------------------------------------------------------------- fused fp32 forward (np/BLAS-exact)
// 512 threads = 8 waves, 64 pts/block. lane = point, wave = 32-col group.
// h[l] lives in global ping-pong buffers, layout [col][pt] (lane-coalesced).
// Writes are read back only by the same block (same CU, own L1) after
// __syncthreads (which drains vmcnt) -> coherent. W[k][c0..c0+31] is
// wave-uniform -> s_load. Each output element is ONE sequential k-ascending
// fmaf chain from 0, bias added after (bit-exact vs np reference).
__global__ void __launch_bounds__(512) fwd_fused_kernel(
    const float* __restrict__ x, const float* __restrict__ y, const float* __restrict__ t,
    const float* __restrict__ Win, const float* __restrict__ b_in,
    const float* __restrict__ Wh, const float* __restrict__ b_h,
    const float* __restrict__ Wout, const float* __restrict__ b_out,
    float* __restrict__ bufA, float* __restrict__ bufB,
    unsigned char* __restrict__ masks, float* __restrict__ out) {
  __shared__ float pscr[8][72];        // 2304 B only

  const int tid = threadIdx.x;
  const int lane = tid & 63;                                    // point in block
  const int w = __builtin_amdgcn_readfirstlane(tid >> 6);       // wave id (uniform)
  const int c0 = w * 32;
  const int p0 = blockIdx.x * 64;
  const int p = p0 + lane;

  // ---- layer 1: dot = z @ Win (k ascending: x,y,t), then + b_in  [bit-exact]
  {
    float xv = x[p], yv = y[p], tv = t[p];
    unsigned m = 0;
#pragma unroll
    for (int e = 0; e < 32; ++e) {
      int c = c0 + e;                  // uniform -> Win reads are scalar
      float dot = fmaf(xv, Win[c], 0.f);
      dot = fmaf(yv, Win[256 + c], dot);
      dot = fmaf(tv, Win[512 + c], dot);
      float a = dot + b_in[c];
      bool pos = a > 0.f;
      bufA[(size_t)c * NPTS + p] = pos ? a : 0.f;   // [col][pt], lane-coalesced
      m |= (pos ? 1u : 0u) << e;
    }
    *(unsigned*)(masks + (size_t)p * 32 + w * 4) = m;
  }
  __syncthreads();                     // h1 visible to all waves (same CU)

  // ---- hidden layers: single fp32 accumulator per element, k ascending, fmaf
  float* bin = bufA;
  float* bout = bufB;
  float hlast[32];
  for (int l = 0; l < 4; ++l) {
    const float* Wl = Wh + (size_t)l * 65536 + c0;   // + uniform col offset
    const float* hp = bin + p;
    float acc[32] = {};
#pragma unroll 2
    for (int k = 0; k < 256; ++k) {
      float h = hp[(size_t)k * NPTS];  // global_load_dword, coalesced (vmcnt)
      const float* wr = Wl + k * 256;  // wave-uniform -> s_load_dwordx16
#pragma unroll
      for (int e = 0; e < 32; ++e)
        acc[e] = fmaf(h, wr[e], acc[e]);
    }
    unsigned m = 0;
#pragma unroll
    for (int e = 0; e < 32; ++e) {
      float a = acc[e] + b_h[l * 256 + c0 + e];
      bool pos = a > 0.f;
      hlast[e] = pos ? a : 0.f;
      m |= (pos ? 1u : 0u) << e;
    }
    *(unsigned*)(masks + ((size_t)(l + 1) * NPTS + p) * 32 + w * 4) = m;
    if (l < 3) {
#pragma unroll
      for (int e = 0; e < 32; ++e)
        bout[(size_t)(c0 + e) * NPTS + p] = hlast[e];
      __syncthreads();                 // drain stores; block-private -> coherent
      float* tmp = bin; bin = bout; bout = tmp;
    }
  }

  // ---- p = h5 . Wout[:,1] + b_out[1]  (h5 still in registers; value output,
  //      order-insensitive at bf16 comparison granularity)
  float s = 0.f;
#pragma unroll
  for (int e = 0; e < 32; ++e)
    s = fmaf(hlast[e], Wout[2 * (c0 + e) + 1], s);
  pscr[w][lane] = s;
  __syncthreads();
  if (tid < 64) {
    float s2 = 0.f;
#pragma unroll
    for (int g = 0; g < 8; ++g) s2 += pscr[g][tid];
    out[2 * NPTS + p0 + tid] = s2 + b_out[1];
  }
}

// ---------------------------------------------------------------- prep: Wh fp32 [l][k][n] -> f16 [l][n][k]
__global__ void __launch_bounds__(256) prep_weights_kernel(
    const float* __restrict__ Wh, _Float16* __restrict__ Wt) {
  int i = blockIdx.x * 256 + threadIdx.x;   // 0..262143
  int l = i >> 16;
  int rem = i & 65535;
  int k = rem >> 8, n = rem & 255;
  Wt[(size_t)(l << 16) + n * 256 + k] = (_Float16)Wh[i];
}

// ---------------------------------------------------------------- fused tangent chain (init + 4 layers + finalize)
// Block: 256 thr = 4 waves. 32 points -> 64 rows (0..31 x-tangent, 32..63 y).
// Tile M=64 x N=256; wave wn owns 64 rows x 64 cols (acc 4x4 16x16 tiles).
// T lives in Apan (f16) across layers; W streamed in 64-k chunks to Bpan.
// mfma_f32_16x16x32_f16: A[m=lane&15][k=quad*8+j], B[k=quad*8+j][n=lane&15],
//                        D[row=quad*4+reg][col=lane&15]  (verified layouts)
__global__ void __launch_bounds__(256, 2) tangent_fused_kernel(
    const float* __restrict__ Win,
    const _Float16* __restrict__ Wt,          // [l][n][k] (pre-transposed)
    const unsigned int* __restrict__ maskDw,  // [5][NPTS][8] dwords
    const float* __restrict__ Wout, float* __restrict__ out) {
  constexpr int SA = 264;   // A row stride (halves): 256 + 8 pad
  constexpr int SB = 72;    // B row stride (halves): 64 + 8 pad
  __shared__ alignas(16) _Float16 Apan[64 * SA];    // 33792 B
  __shared__ alignas(16) _Float16 Bpan[256 * SB];   // 36864 B
  __shared__ unsigned int smask[5 * 256];           // 5120 B

  const int tid = threadIdx.x;
  const int lane = tid & 63;
  const int wn = tid >> 6;          // wave = 64-col group
  const int l15 = lane & 15, quad = lane >> 4;
  const int p0 = blockIdx.x * 32;   // 32 points per block

  // ---- stage all 5 mask layers (32 pts x 8 dw each)
#pragma unroll
  for (int i = 0; i < 5; ++i)
    smask[i * 256 + tid] = maskDw[(size_t)i * NPTS * 8 + (size_t)p0 * 8 + tid];
  __syncthreads();

  // ---- init T1 into Apan: row<32 -> x-tangent (Win row 0), row>=32 -> y (row 1)
#pragma unroll
  for (int i = 0; i < 8; ++i) {
    int g = tid + 256 * i;          // 0..2047 col-groups of 8
    int row = g >> 5, cg = g & 31;
    int c0 = cg * 8, pt = row & 31, tg = row >> 5;
    unsigned dw = smask[pt * 8 + (c0 >> 5)];
    half8_t v;
#pragma unroll
    for (int e = 0; e < 8; ++e) {
      bool m = (dw >> ((cg & 3) * 8 + e)) & 1;
      v[e] = m ? (_Float16)Win[tg * 256 + c0 + e] : (_Float16)0.f;
    }
    *(half8_t*)&Apan[row * SA + c0] = v;
  }

  // ---- 4 layers: acc = A @ W_l, gate by mask[l+1], back into Apan as f16
  for (int l = 0; l < 4; ++l) {
    const _Float16* Wl = Wt + (size_t)l * 65536;
    floatx4 acc[4][4] = {};   // [mi][nj]
    for (int kp = 0; kp < 4; ++kp) {
      __syncthreads();        // Bpan free (and Apan init/writes visible)
      // stage B chunk: 256 n-rows x 64 k halves
#pragma unroll
      for (int i = 0; i < 8; ++i) {
        int g = tid + 256 * i;      // 0..2047 half8 segs
        int row = g >> 3, seg = g & 7;
        *(half8_t*)&Bpan[row * SB + seg * 8] =
            *(const half8_t*)(Wl + (size_t)row * 256 + kp * 64 + seg * 8);
      }
      __syncthreads();
#pragma unroll
      for (int ks = 0; ks < 2; ++ks) {
        half8_t af[4], bf[4];
#pragma unroll
        for (int mi = 0; mi < 4; ++mi)
          af[mi] = *(const half8_t*)&Apan[(mi * 16 + l15) * SA + kp * 64 + ks * 32 + quad * 8];
#pragma unroll
        for (int nj = 0; nj < 4; ++nj)
          bf[nj] = *(const half8_t*)&Bpan[(wn * 64 + nj * 16 + l15) * SB + ks * 32 + quad * 8];
#pragma unroll
        for (int mi = 0; mi < 4; ++mi)
#pragma unroll
          for (int nj = 0; nj < 4; ++nj)
            acc[mi][nj] = __builtin_amdgcn_mfma_f32_16x16x32_f16(af[mi], bf[nj], acc[mi][nj], 0, 0, 0);
      }
    }
    __syncthreads();          // all Apan reads of this layer done
    // gated write-back (C layout -> A storage), f16
    const unsigned int* ml = &smask[(l + 1) * 256];
#pragma unroll
    for (int mi = 0; mi < 4; ++mi) {
#pragma unroll
      for (int r = 0; r < 4; ++r) {
        int row = mi * 16 + quad * 4 + r;
        int pt = row & 31;
#pragma unroll
        for (int nj = 0; nj < 4; ++nj) {
          int C = wn * 64 + nj * 16 + l15;
          bool m = (ml[pt * 8 + (C >> 5)] >> (C & 31)) & 1;
          Apan[row * SA + C] = m ? (_Float16)acc[mi][nj][r] : (_Float16)0.f;
        }
      }
    }
    __syncthreads();
  }

  // ---- finalize from Apan (= T5 gated): per row, dots with Wout cols
  float4 wA = *(const float4*)(Wout + lane * 8);      // (W[c][0],W[c][1],W[c+1][0],W[c+1][1])
  float4 wB = *(const float4*)(Wout + lane * 8 + 4);
  float w0[4] = {wA.x, wA.z, wB.x, wB.z};  // Wout[:,0] for cols lane*4..+3
  float w1[4] = {wA.y, wA.w, wB.y, wB.w};  // Wout[:,1]
#pragma unroll
  for (int i = 0; i < 16; ++i) {
    int row = wn * 16 + i;
    half4_t hv = *(const half4_t*)&Apan[row * SA + lane * 4];
    float s0 = 0.f, s1 = 0.f;
#pragma unroll
    for (int e = 0; e < 4; ++e) {
      float fv = (float)hv[e];
      s0 = fmaf(fv, w0[e], s0);
      s1 = fmaf(fv, w1[e], s1);
    }
#pragma unroll
    for (int off = 1; off < 64; off <<= 1) {
      s0 += __shfl_xor(s0, off);
      s1 += __shfl_xor(s1, off);
    }
    if (lane == 0) {
      int pt = p0 + (row & 31);
      if (row < 32) {                 // x-tangent: v = -psi_x, f = p_x
        out[NPTS + pt] = -s0;
        out[3 * NPTS + pt] = s1;
      } else {                        // y-tangent: u = psi_y, g = p_y
        out[pt] = s0;
        out[4 * NPTS + pt] = s1;
      }
    }
  }
}

// ---------------------------------------------------------------- launch
extern "C" void kernel_launch(void* const* d_in, const int* in_sizes, int n_in,
                              void* d_out, int out_size, void* d_ws, size_t ws_size,
                              hipStream_t stream) {
  const float* x = (const float*)d_in[0];
  const float* y = (const float*)d_in[1];
  const float* t = (const float*)d_in[2];
  const float* Win = (const float*)d_in[3];
  const float* b_in = (const float*)d_in[4];
  const float* Wh = (const float*)d_in[5];
  const float* b_h = (const float*)d_in[6];
  const float* Wout = (const float*)d_in[7];
  const float* b_out = (const float*)d_in[8];
  float* out = (float*)d_out;

  char* ws = (char*)d_ws;
  constexpr size_t BUF_SZ = (size_t)NPTS * 256 * 4;   // 64 MB fp32 h buffer
  constexpr size_t MASK_SZ = (size_t)NPTS * 32;       // 2 MB per layer
  float* bufA = (float*)ws;
  float* bufB = (float*)(ws + BUF_SZ);
  unsigned char* masks = (unsigned char*)(ws + 2 * BUF_SZ);
  _Float16* Wt = (_Float16*)(ws + 2 * BUF_SZ + 5 * MASK_SZ);

  // weight transpose/cast first (independent of fwd)
  prep_weights_kernel<<<1024, 256, 0, stream>>>(Wh, Wt);

  // fp32 np-exact forward: masks L0..L4 + p
  fwd_fused_kernel<<<NPTS / 64, 512, 0, stream>>>(
      x, y, t, Win, b_in, Wh, b_h, Wout, b_out, bufA, bufB, masks, out);

  // fused tangent chain: init + 4 MFMA layers + finalize (u,v,f,g)
  tangent_fused_kernel<<<NPTS / 32, 256, 0, stream>>>(
      Win, Wt, (const unsigned int*)masks, Wout, out);
}

// Round 9
// 653.047 us; speedup vs baseline: 1.2647x; 1.2647x over previous
//
#include <hip/hip_runtime.h>
#include <hip/hip_bf16.h>

// N=65536 points, H=256, 4 hidden layers, ReLU MLP -> (psi,p).
// ReLU => piecewise linear => Hessians vanish; f = p_x, g = p_y (RHO=1).
// Pipeline:
//   1) fp32 forward replicating np/BLAS arithmetic BIT-EXACTLY
//      (k-ascending single-acc fmaf chain, bias after, mask = a>0).
//      v9: v6 LDS structure but 1024 thr = 16 waves of 16-col groups ->
//      8 waves/SIMD so the SMEM/LDS lgkmcnt drains are hidden by TLP
//      (v6 stalled at 56% VALUBusy with 4 waves/SIMD; v8's global-h
//      detour regressed to 44% via HBM latency - reverted).
//   2) ONE fused tangent kernel (v7): T1 init from masks+Win, 4 MFMA
//      layers with mask-gated f16 LDS roundtrip, fused finalize.
// Workspace: masks 5x2MB | Wt 512KB

#define NPTS 65536
#define HDIM 256

typedef _Float16 half8_t __attribute__((ext_vector_type(8)));
typedef _Float16 half4_t __attribute__((ext_vector_type(4)));
typedef float floatx4 __attribute__((ext_vector_type(4)));

// ---------------------------------------------------------------- fused fp32 forward (np/BLAS-exact)
// 1024 threads = 16 waves, 64 pts/block. lane = point, wave = 16-col group.
// W[k][c0..c0+15] is wave-uniform -> one s_load_dwordx16 per k, no W staging.
// hT[pt][k] stride 257 (odd -> conflict-free b32). Each output element is ONE
// sequential k-ascending fmaf chain from 0, bias added after (bit-exact vs np).
__global__ void __launch_bounds__(1024) fwd_fused_kernel(
    const float* __restrict__ x, const float* __restrict__ y, const float* __restrict__ t,
    const float* __restrict__ Win, const float* __restrict__ b_in,
    const float* __restrict__ Wh, const float* __restrict__ b_h,
    const float* __restrict__ Wout, const float* __restrict__ b_out,
    unsigned char* __restrict__ masks, float* __restrict__ out) {
  constexpr int SH = 257;              // odd stride: conflict-free b32
  __shared__ float hT[64 * SH];        // [pt][k]  65792 B
  __shared__ float pscr[16][72];       // wave partials for p (4608 B)

  const int tid = threadIdx.x;
  const int lane = tid & 63;                                    // point in block
  const int w = __builtin_amdgcn_readfirstlane(tid >> 6);       // wave id 0..15
  const int c0 = w * 16;                                        // 16-col group
  const int p0 = blockIdx.x * 64;
  const int p = p0 + lane;

  // ---- layer 1: dot = z @ Win (k ascending: x,y,t), then + b_in  [bit-exact]
  {
    float xv = x[p], yv = y[p], tv = t[p];
    unsigned m = 0;
#pragma unroll
    for (int e = 0; e < 16; ++e) {
      int c = c0 + e;                  // uniform -> Win reads are scalar
      float dot = fmaf(xv, Win[c], 0.f);
      dot = fmaf(yv, Win[256 + c], dot);
      dot = fmaf(tv, Win[512 + c], dot);
      float a = dot + b_in[c];
      bool pos = a > 0.f;
      hT[lane * SH + c] = pos ? a : 0.f;
      m |= (pos ? 1u : 0u) << e;
    }
    *(unsigned short*)(masks + (size_t)p * 32 + w * 2) = (unsigned short)m;
  }
  __syncthreads();

  // ---- hidden layers: single fp32 accumulator per element, k ascending, fmaf
  for (int l = 0; l < 4; ++l) {
    const float* Wl = Wh + (size_t)l * 65536 + c0;   // + uniform col offset
    float acc[16] = {};
#pragma unroll 2
    for (int k = 0; k < 256; ++k) {
      float h = hT[lane * SH + k];     // per-lane LDS, conflict-free
      const float* wr = Wl + k * 256;  // wave-uniform -> s_load_dwordx16
#pragma unroll
      for (int e = 0; e < 16; ++e)
        acc[e] = fmaf(h, wr[e], acc[e]);
    }
    __syncthreads();                   // all hT reads done before overwrite
    unsigned m = 0;
    float hnew[16];
#pragma unroll
    for (int e = 0; e < 16; ++e) {
      float a = acc[e] + b_h[l * 256 + c0 + e];
      bool pos = a > 0.f;
      hnew[e] = pos ? a : 0.f;
      m |= (pos ? 1u : 0u) << e;
    }
    *(unsigned short*)(masks + ((size_t)(l + 1) * NPTS + p) * 32 + w * 2) =
        (unsigned short)m;
#pragma unroll
    for (int e = 0; e < 16; ++e)
      hT[lane * SH + c0 + e] = hnew[e];
    __syncthreads();
  }

  // ---- p = h5 . Wout[:,1] + b_out[1]  (value output; order-insensitive at
  //      bf16 comparison granularity)
  float s = 0.f;
#pragma unroll
  for (int e = 0; e < 16; ++e)
    s = fmaf(hT[lane * SH + c0 + e], Wout[2 * (c0 + e) + 1], s);
  pscr[w][lane] = s;
  __syncthreads();
  if (tid < 64) {
    float s2 = 0.f;
#pragma unroll
    for (int g = 0; g < 16; ++g) s2 += pscr[g][tid];
    out[2 * NPTS + p0 + tid] = s2 + b_out[1];
  }
}

// ---------------------------------------------------------------- prep: Wh fp32 [l][k][n] -> f16 [l][n][k]
__global__ void __launch_bounds__(256) prep_weights_kernel(
    const float* __restrict__ Wh, _Float16* __restrict__ Wt) {
  int i = blockIdx.x * 256 + threadIdx.x;   // 0..262143
  int l = i >> 16;
  int rem = i & 65535;
  int k = rem >> 8, n = rem & 255;
  Wt[(size_t)(l << 16) + n * 256 + k] = (_Float16)Wh[i];
}

// ---------------------------------------------------------------- fused tangent chain (init + 4 layers + finalize)
// Block: 256 thr = 4 waves. 32 points -> 64 rows (0..31 x-tangent, 32..63 y).
// Tile M=64 x N=256; wave wn owns 64 rows x 64 cols (acc 4x4 16x16 tiles).
// T lives in Apan (f16) across layers; W streamed in 64-k chunks to Bpan.
// mfma_f32_16x16x32_f16: A[m=lane&15][k=quad*8+j], B[k=quad*8+j][n=lane&15],
//                        D[row=quad*4+reg][col=lane&15]  (verified layouts)
__global__ void __launch_bounds__(256, 2) tangent_fused_kernel(
    const float* __restrict__ Win,
    const _Float16* __restrict__ Wt,          // [l][n][k] (pre-transposed)
    const unsigned int* __restrict__ maskDw,  // [5][NPTS][8] dwords
    const float* __restrict__ Wout, float* __restrict__ out) {
  constexpr int SA = 264;   // A row stride (halves): 256 + 8 pad
  constexpr int SB = 72;    // B row stride (halves): 64 + 8 pad
  __shared__ alignas(16) _Float16 Apan[64 * SA];    // 33792 B
  __shared__ alignas(16) _Float16 Bpan[256 * SB];   // 36864 B
  __shared__ unsigned int smask[5 * 256];           // 5120 B

  const int tid = threadIdx.x;
  const int lane = tid & 63;
  const int wn = tid >> 6;          // wave = 64-col group
  const int l15 = lane & 15, quad = lane >> 4;
  const int p0 = blockIdx.x * 32;   // 32 points per block

  // ---- stage all 5 mask layers (32 pts x 8 dw each)
#pragma unroll
  for (int i = 0; i < 5; ++i)
    smask[i * 256 + tid] = maskDw[(size_t)i * NPTS * 8 + (size_t)p0 * 8 + tid];
  __syncthreads();

  // ---- init T1 into Apan: row<32 -> x-tangent (Win row 0), row>=32 -> y (row 1)
#pragma unroll
  for (int i = 0; i < 8; ++i) {
    int g = tid + 256 * i;          // 0..2047 col-groups of 8
    int row = g >> 5, cg = g & 31;
    int c0 = cg * 8, pt = row & 31, tg = row >> 5;
    unsigned dw = smask[pt * 8 + (c0 >> 5)];
    half8_t v;
#pragma unroll
    for (int e = 0; e < 8; ++e) {
      bool m = (dw >> ((cg & 3) * 8 + e)) & 1;
      v[e] = m ? (_Float16)Win[tg * 256 + c0 + e] : (_Float16)0.f;
    }
    *(half8_t*)&Apan[row * SA + c0] = v;
  }

  // ---- 4 layers: acc = A @ W_l, gate by mask[l+1], back into Apan as f16
  for (int l = 0; l < 4; ++l) {
    const _Float16* Wl = Wt + (size_t)l * 65536;
    floatx4 acc[4][4] = {};   // [mi][nj]
    for (int kp = 0; kp < 4; ++kp) {
      __syncthreads();        // Bpan free (and Apan init/writes visible)
      // stage B chunk: 256 n-rows x 64 k halves
#pragma unroll
      for (int i = 0; i < 8; ++i) {
        int g = tid + 256 * i;      // 0..2047 half8 segs
        int row = g >> 3, seg = g & 7;
        *(half8_t*)&Bpan[row * SB + seg * 8] =
            *(const half8_t*)(Wl + (size_t)row * 256 + kp * 64 + seg * 8);
      }
      __syncthreads();
#pragma unroll
      for (int ks = 0; ks < 2; ++ks) {
        half8_t af[4], bf[4];
#pragma unroll
        for (int mi = 0; mi < 4; ++mi)
          af[mi] = *(const half8_t*)&Apan[(mi * 16 + l15) * SA + kp * 64 + ks * 32 + quad * 8];
#pragma unroll
        for (int nj = 0; nj < 4; ++nj)
          bf[nj] = *(const half8_t*)&Bpan[(wn * 64 + nj * 16 + l15) * SB + ks * 32 + quad * 8];
#pragma unroll
        for (int mi = 0; mi < 4; ++mi)
#pragma unroll
          for (int nj = 0; nj < 4; ++nj)
            acc[mi][nj] = __builtin_amdgcn_mfma_f32_16x16x32_f16(af[mi], bf[nj], acc[mi][nj], 0, 0, 0);
      }
    }
    __syncthreads();          // all Apan reads of this layer done
    // gated write-back (C layout -> A storage), f16
    const unsigned int* ml = &smask[(l + 1) * 256];
#pragma unroll
    for (int mi = 0; mi < 4; ++mi) {
#pragma unroll
      for (int r = 0; r < 4; ++r) {
        int row = mi * 16 + quad * 4 + r;
        int pt = row & 31;
#pragma unroll
        for (int nj = 0; nj < 4; ++nj) {
          int C = wn * 64 + nj * 16 + l15;
          bool m = (ml[pt * 8 + (C >> 5)] >> (C & 31)) & 1;
          Apan[row * SA + C] = m ? (_Float16)acc[mi][nj][r] : (_Float16)0.f;
        }
      }
    }
    __syncthreads();
  }

  // ---- finalize from Apan (= T5 gated): per row, dots with Wout cols
  float4 wA = *(const float4*)(Wout + lane * 8);      // (W[c][0],W[c][1],W[c+1][0],W[c+1][1])
  float4 wB = *(const float4*)(Wout + lane * 8 + 4);
  float w0[4] = {wA.x, wA.z, wB.x, wB.z};  // Wout[:,0] for cols lane*4..+3
  float w1[4] = {wA.y, wA.w, wB.y, wB.w};  // Wout[:,1]
#pragma unroll
  for (int i = 0; i < 16; ++i) {
    int row = wn * 16 + i;
    half4_t hv = *(const half4_t*)&Apan[row * SA + lane * 4];
    float s0 = 0.f, s1 = 0.f;
#pragma unroll
    for (int e = 0; e < 4; ++e) {
      float fv = (float)hv[e];
      s0 = fmaf(fv, w0[e], s0);
      s1 = fmaf(fv, w1[e], s1);
    }
#pragma unroll
    for (int off = 1; off < 64; off <<= 1) {
      s0 += __shfl_xor(s0, off);
      s1 += __shfl_xor(s1, off);
    }
    if (lane == 0) {
      int pt = p0 + (row & 31);
      if (row < 32) {                 // x-tangent: v = -psi_x, f = p_x
        out[NPTS + pt] = -s0;
        out[3 * NPTS + pt] = s1;
      } else {                        // y-tangent: u = psi_y, g = p_y
        out[pt] = s0;
        out[4 * NPTS + pt] = s1;
      }
    }
  }
}

// ---------------------------------------------------------------- launch
extern "C" void kernel_launch(void* const* d_in, const int* in_sizes, int n_in,
                              void* d_out, int out_size, void* d_ws, size_t ws_size,
                              hipStream_t stream) {
  const float* x = (const float*)d_in[0];
  const float* y = (const float*)d_in[1];
  const float* t = (const float*)d_in[2];
  const float* Win = (const float*)d_in[3];
  const float* b_in = (const float*)d_in[4];
  const float* Wh = (const float*)d_in[5];
  const float* b_h = (const float*)d_in[6];
  const float* Wout = (const float*)d_in[7];
  const float* b_out = (const float*)d_in[8];
  float* out = (float*)d_out;

  char* ws = (char*)d_ws;
  constexpr size_t MASK_SZ = (size_t)NPTS * 32;       // 2 MB per layer
  unsigned char* masks = (unsigned char*)ws;
  _Float16* Wt = (_Float16*)(ws + 5 * MASK_SZ);

  // weight transpose/cast first (independent of fwd)
  prep_weights_kernel<<<1024, 256, 0, stream>>>(Wh, Wt);

  // fp32 np-exact forward: masks L0..L4 + p
  fwd_fused_kernel<<<NPTS / 64, 1024, 0, stream>>>(
      x, y, t, Win, b_in, Wh, b_h, Wout, b_out, masks, out);

  // fused tangent chain: init + 4 MFMA layers + finalize (u,v,f,g)
  tangent_fused_kernel<<<NPTS / 32, 256, 0, stream>>>(
      Win, Wt, (const unsigned int*)masks, Wout, out);
}

// Round 10
// 596.695 us; speedup vs baseline: 1.3841x; 1.0944x over previous
//
#include <hip/hip_runtime.h>
#include <hip/hip_bf16.h>

// N=65536 points, H=256, 4 hidden layers, ReLU MLP -> (psi,p).
// ReLU => piecewise linear => Hessians vanish; f = p_x, g = p_y (RHO=1).
// Pipeline:
//   1) fp32 forward replicating np/BLAS arithmetic BIT-EXACTLY
//      (k-ascending single-acc chain, bias after, mask = a>0).
//      v10: v6 mapping (lane=point, wave=32-col, W via wave-uniform s_load)
//      but the inner FMAs are PACKED fp32 (v_pk_fma_f32 via <2 x float>
//      __builtin_elementwise_fma) — IEEE-identical per half, half the
//      VALU issue slots. v6-v9 showed the fwd is VALU-ISSUE-bound at the
//      scalar v_fma_f32 rate (74 TF achieved ~ 95% of scalar ceiling);
//      fp32 peak 157 TF requires packed math.
//   2) ONE fused tangent kernel (v7): T1 init from masks+Win, 4 MFMA
//      layers with mask-gated f16 LDS roundtrip, fused finalize.
// Workspace: masks 5x2MB | Wt 512KB

#define NPTS 65536
#define HDIM 256

typedef _Float16 half8_t __attribute__((ext_vector_type(8)));
typedef _Float16 half4_t __attribute__((ext_vector_type(4)));
typedef float floatx4 __attribute__((ext_vector_type(4)));
typedef float float2v __attribute__((ext_vector_type(2)));

// ---------------------------------------------------------------- fused fp32 forward (np/BLAS-exact, packed fp32)
// 512 threads = 8 waves, 64 pts/block. lane = point, wave = 32-col group.
// W[k][c0..c0+31] wave-uniform -> s_load; hT[pt][k] stride 257 (conflict-free).
// Each output element is ONE sequential k-ascending fma chain from 0 (each
// FMA is one half of a v_pk_fma_f32 — IEEE-identical to fmaf), bias added
// after (bit-exact vs np reference). Writes masks L0..L4 + p output.
__global__ void __launch_bounds__(512) fwd_fused_kernel(
    const float* __restrict__ x, const float* __restrict__ y, const float* __restrict__ t,
    const float* __restrict__ Win, const float* __restrict__ b_in,
    const float* __restrict__ Wh, const float* __restrict__ b_h,
    const float* __restrict__ Wout, const float* __restrict__ b_out,
    unsigned char* __restrict__ masks, float* __restrict__ out) {
  constexpr int SH = 257;              // odd stride: conflict-free b32
  __shared__ float hT[64 * SH];        // [pt][k]  65792 B
  __shared__ float pscr[8][72];        // wave partials for p (2304 B)

  const int tid = threadIdx.x;
  const int lane = tid & 63;                                    // point in block
  const int w = __builtin_amdgcn_readfirstlane(tid >> 6);       // wave id (uniform)
  const int c0 = w * 32;
  const int p0 = blockIdx.x * 64;
  const int p = p0 + lane;

  // ---- layer 1: dot = z @ Win (k ascending: x,y,t), then + b_in  [bit-exact]
  {
    float xv = x[p], yv = y[p], tv = t[p];
    unsigned m = 0;
#pragma unroll
    for (int e = 0; e < 32; ++e) {
      int c = c0 + e;                  // uniform -> Win reads are scalar
      float dot = fmaf(xv, Win[c], 0.f);
      dot = fmaf(yv, Win[256 + c], dot);
      dot = fmaf(tv, Win[512 + c], dot);
      float a = dot + b_in[c];
      bool pos = a > 0.f;
      hT[lane * SH + c] = pos ? a : 0.f;
      m |= (pos ? 1u : 0u) << e;
    }
    *(unsigned*)(masks + (size_t)p * 32 + w * 4) = m;
  }
  __syncthreads();

  // ---- hidden layers: packed fp32 chain per element (k ascending), bias after
  for (int l = 0; l < 4; ++l) {
    const float* Wl = Wh + (size_t)l * 65536 + c0;   // + uniform col offset
    float2v acc[16] = {};              // col pairs (c0+2e, c0+2e+1)
#pragma unroll 2
    for (int k = 0; k < 256; ++k) {
      float h = hT[lane * SH + k];     // per-lane LDS, conflict-free
      const float* wr = Wl + k * 256;  // wave-uniform -> s_load
      float2v hv = {h, h};
#pragma unroll
      for (int e = 0; e < 16; ++e) {
        float2v wv = *(const float2v*)(wr + 2 * e);   // scalar pair (SGPR x2)
        acc[e] = __builtin_elementwise_fma(hv, wv, acc[e]);  // v_pk_fma_f32
      }
    }
    __syncthreads();                   // all hT reads done before overwrite
    unsigned m = 0;
    float hnew[32];
#pragma unroll
    for (int e = 0; e < 32; ++e) {
      float a = acc[e >> 1][e & 1] + b_h[l * 256 + c0 + e];
      bool pos = a > 0.f;
      hnew[e] = pos ? a : 0.f;
      m |= (pos ? 1u : 0u) << e;
    }
    *(unsigned*)(masks + ((size_t)(l + 1) * NPTS + p) * 32 + w * 4) = m;
#pragma unroll
    for (int e = 0; e < 32; ++e)
      hT[lane * SH + c0 + e] = hnew[e];
    __syncthreads();
  }

  // ---- p = h5 . Wout[:,1] + b_out[1]  (value output; order-insensitive at
  //      bf16 comparison granularity)
  float s = 0.f;
#pragma unroll
  for (int e = 0; e < 32; ++e)
    s = fmaf(hT[lane * SH + c0 + e], Wout[2 * (c0 + e) + 1], s);
  pscr[w][lane] = s;
  __syncthreads();
  if (tid < 64) {
    float s2 = 0.f;
#pragma unroll
    for (int g = 0; g < 8; ++g) s2 += pscr[g][tid];
    out[2 * NPTS + p0 + tid] = s2 + b_out[1];
  }
}

// ---------------------------------------------------------------- prep: Wh fp32 [l][k][n] -> f16 [l][n][k]
__global__ void __launch_bounds__(256) prep_weights_kernel(
    const float* __restrict__ Wh, _Float16* __restrict__ Wt) {
  int i = blockIdx.x * 256 + threadIdx.x;   // 0..262143
  int l = i >> 16;
  int rem = i & 65535;
  int k = rem >> 8, n = rem & 255;
  Wt[(size_t)(l << 16) + n * 256 + k] = (_Float16)Wh[i];
}

// ---------------------------------------------------------------- fused tangent chain (init + 4 layers + finalize)
// Block: 256 thr = 4 waves. 32 points -> 64 rows (0..31 x-tangent, 32..63 y).
// Tile M=64 x N=256; wave wn owns 64 rows x 64 cols (acc 4x4 16x16 tiles).
// T lives in Apan (f16) across layers; W streamed in 64-k chunks to Bpan.
// mfma_f32_16x16x32_f16: A[m=lane&15][k=quad*8+j], B[k=quad*8+j][n=lane&15],
//                        D[row=quad*4+reg][col=lane&15]  (verified layouts)
__global__ void __launch_bounds__(256, 2) tangent_fused_kernel(
    const float* __restrict__ Win,
    const _Float16* __restrict__ Wt,          // [l][n][k] (pre-transposed)
    const unsigned int* __restrict__ maskDw,  // [5][NPTS][8] dwords
    const float* __restrict__ Wout, float* __restrict__ out) {
  constexpr int SA = 264;   // A row stride (halves): 256 + 8 pad
  constexpr int SB = 72;    // B row stride (halves): 64 + 8 pad
  __shared__ alignas(16) _Float16 Apan[64 * SA];    // 33792 B
  __shared__ alignas(16) _Float16 Bpan[256 * SB];   // 36864 B
  __shared__ unsigned int smask[5 * 256];           // 5120 B

  const int tid = threadIdx.x;
  const int lane = tid & 63;
  const int wn = tid >> 6;          // wave = 64-col group
  const int l15 = lane & 15, quad = lane >> 4;
  const int p0 = blockIdx.x * 32;   // 32 points per block

  // ---- stage all 5 mask layers (32 pts x 8 dw each)
#pragma unroll
  for (int i = 0; i < 5; ++i)
    smask[i * 256 + tid] = maskDw[(size_t)i * NPTS * 8 + (size_t)p0 * 8 + tid];
  __syncthreads();

  // ---- init T1 into Apan: row<32 -> x-tangent (Win row 0), row>=32 -> y (row 1)
#pragma unroll
  for (int i = 0; i < 8; ++i) {
    int g = tid + 256 * i;          // 0..2047 col-groups of 8
    int row = g >> 5, cg = g & 31;
    int c0 = cg * 8, pt = row & 31, tg = row >> 5;
    unsigned dw = smask[pt * 8 + (c0 >> 5)];
    half8_t v;
#pragma unroll
    for (int e = 0; e < 8; ++e) {
      bool m = (dw >> ((cg & 3) * 8 + e)) & 1;
      v[e] = m ? (_Float16)Win[tg * 256 + c0 + e] : (_Float16)0.f;
    }
    *(half8_t*)&Apan[row * SA + c0] = v;
  }

  // ---- 4 layers: acc = A @ W_l, gate by mask[l+1], back into Apan as f16
  for (int l = 0; l < 4; ++l) {
    const _Float16* Wl = Wt + (size_t)l * 65536;
    floatx4 acc[4][4] = {};   // [mi][nj]
    for (int kp = 0; kp < 4; ++kp) {
      __syncthreads();        // Bpan free (and Apan init/writes visible)
      // stage B chunk: 256 n-rows x 64 k halves
#pragma unroll
      for (int i = 0; i < 8; ++i) {
        int g = tid + 256 * i;      // 0..2047 half8 segs
        int row = g >> 3, seg = g & 7;
        *(half8_t*)&Bpan[row * SB + seg * 8] =
            *(const half8_t*)(Wl + (size_t)row * 256 + kp * 64 + seg * 8);
      }
      __syncthreads();
#pragma unroll
      for (int ks = 0; ks < 2; ++ks) {
        half8_t af[4], bf[4];
#pragma unroll
        for (int mi = 0; mi < 4; ++mi)
          af[mi] = *(const half8_t*)&Apan[(mi * 16 + l15) * SA + kp * 64 + ks * 32 + quad * 8];
#pragma unroll
        for (int nj = 0; nj < 4; ++nj)
          bf[nj] = *(const half8_t*)&Bpan[(wn * 64 + nj * 16 + l15) * SB + ks * 32 + quad * 8];
#pragma unroll
        for (int mi = 0; mi < 4; ++mi)
#pragma unroll
          for (int nj = 0; nj < 4; ++nj)
            acc[mi][nj] = __builtin_amdgcn_mfma_f32_16x16x32_f16(af[mi], bf[nj], acc[mi][nj], 0, 0, 0);
      }
    }
    __syncthreads();          // all Apan reads of this layer done
    // gated write-back (C layout -> A storage), f16
    const unsigned int* ml = &smask[(l + 1) * 256];
#pragma unroll
    for (int mi = 0; mi < 4; ++mi) {
#pragma unroll
      for (int r = 0; r < 4; ++r) {
        int row = mi * 16 + quad * 4 + r;
        int pt = row & 31;
#pragma unroll
        for (int nj = 0; nj < 4; ++nj) {
          int C = wn * 64 + nj * 16 + l15;
          bool m = (ml[pt * 8 + (C >> 5)] >> (C & 31)) & 1;
          Apan[row * SA + C] = m ? (_Float16)acc[mi][nj][r] : (_Float16)0.f;
        }
      }
    }
    __syncthreads();
  }

  // ---- finalize from Apan (= T5 gated): per row, dots with Wout cols
  float4 wA = *(const float4*)(Wout + lane * 8);      // (W[c][0],W[c][1],W[c+1][0],W[c+1][1])
  float4 wB = *(const float4*)(Wout + lane * 8 + 4);
  float w0[4] = {wA.x, wA.z, wB.x, wB.z};  // Wout[:,0] for cols lane*4..+3
  float w1[4] = {wA.y, wA.w, wB.y, wB.w};  // Wout[:,1]
#pragma unroll
  for (int i = 0; i < 16; ++i) {
    int row = wn * 16 + i;
    half4_t hv = *(const half4_t*)&Apan[row * SA + lane * 4];
    float s0 = 0.f, s1 = 0.f;
#pragma unroll
    for (int e = 0; e < 4; ++e) {
      float fv = (float)hv[e];
      s0 = fmaf(fv, w0[e], s0);
      s1 = fmaf(fv, w1[e], s1);
    }
#pragma unroll
    for (int off = 1; off < 64; off <<= 1) {
      s0 += __shfl_xor(s0, off);
      s1 += __shfl_xor(s1, off);
    }
    if (lane == 0) {
      int pt = p0 + (row & 31);
      if (row < 32) {                 // x-tangent: v = -psi_x, f = p_x
        out[NPTS + pt] = -s0;
        out[3 * NPTS + pt] = s1;
      } else {                        // y-tangent: u = psi_y, g = p_y
        out[pt] = s0;
        out[4 * NPTS + pt] = s1;
      }
    }
  }
}

// ---------------------------------------------------------------- launch
extern "C" void kernel_launch(void* const* d_in, const int* in_sizes, int n_in,
                              void* d_out, int out_size, void* d_ws, size_t ws_size,
                              hipStream_t stream) {
  const float* x = (const float*)d_in[0];
  const float* y = (const float*)d_in[1];
  const float* t = (const float*)d_in[2];
  const float* Win = (const float*)d_in[3];
  const float* b_in = (const float*)d_in[4];
  const float* Wh = (const float*)d_in[5];
  const float* b_h = (const float*)d_in[6];
  const float* Wout = (const float*)d_in[7];
  const float* b_out = (const float*)d_in[8];
  float* out = (float*)d_out;

  char* ws = (char*)d_ws;
  constexpr size_t MASK_SZ = (size_t)NPTS * 32;       // 2 MB per layer
  unsigned char* masks = (unsigned char*)ws;
  _Float16* Wt = (_Float16*)(ws + 5 * MASK_SZ);

  // weight transpose/cast first (independent of fwd)
  prep_weights_kernel<<<1024, 256, 0, stream>>>(Wh, Wt);

  // fp32 np-exact forward (packed fp32): masks L0..L4 + p
  fwd_fused_kernel<<<NPTS / 64, 512, 0, stream>>>(
      x, y, t, Win, b_in, Wh, b_h, Wout, b_out, masks, out);

  // fused tangent chain: init + 4 MFMA layers + finalize (u,v,f,g)
  tangent_fused_kernel<<<NPTS / 32, 256, 0, stream>>>(
      Win, Wt, (const unsigned int*)masks, Wout, out);
}

// Round 11
// 565.829 us; speedup vs baseline: 1.4597x; 1.0546x over previous
//
#include <hip/hip_runtime.h>
#include <hip/hip_bf16.h>

// N=65536 points, H=256, 4 hidden layers, ReLU MLP -> (psi,p).
// ReLU => piecewise linear => Hessians vanish; f = p_x, g = p_y (RHO=1).
// Pipeline:
//   1) fp32 forward replicating np/BLAS arithmetic BIT-EXACTLY
//      (k-ascending single-acc fmaf chain, bias after, mask = a>0).
//      v11: 2 POINTS PER LANE. All prior configs pinned at ~55% VALUBusy
//      because the scalar K$ delivers only ~4.3 B/cyc/CU and each W element
//      fed just 64 FMAs (scalar demand 8 B/cyc at VALU sat). With 2 pts/lane
//      each W element feeds 128 FMAs -> demand 4 B/cyc = supply.
//      Block = 1024 thr = 16 waves x 16 cols, 128 pts; hT[128][257] fp32
//      (131.5 KB LDS), 4 waves/SIMD.
//   2) ONE fused tangent kernel (v7): T1 init from masks+Win, 4 MFMA
//      layers with mask-gated f16 LDS roundtrip, fused finalize.
// Workspace: masks 5x2MB | Wt 512KB

#define NPTS 65536
#define HDIM 256

typedef _Float16 half8_t __attribute__((ext_vector_type(8)));
typedef _Float16 half4_t __attribute__((ext_vector_type(4)));
typedef float floatx4 __attribute__((ext_vector_type(4)));

// ---------------------------------------------------------------- fused fp32 forward (np/BLAS-exact)
// 1024 threads = 16 waves, 128 pts/block. lane -> points (p0+lane, p0+64+lane);
// wave w -> cols c0=w*16 (W row slice wave-uniform -> s_load_dwordx16).
// hT[pt][k] stride 257 (odd -> conflict-free). Each output element is ONE
// sequential k-ascending fmaf chain from 0, bias added after (bit-exact vs np).
__global__ void __launch_bounds__(1024) fwd_fused_kernel(
    const float* __restrict__ x, const float* __restrict__ y, const float* __restrict__ t,
    const float* __restrict__ Win, const float* __restrict__ b_in,
    const float* __restrict__ Wh, const float* __restrict__ b_h,
    const float* __restrict__ Wout, const float* __restrict__ b_out,
    unsigned char* __restrict__ masks, float* __restrict__ out) {
  constexpr int SH = 257;              // odd stride: conflict-free b32
  __shared__ float hT[128 * SH];       // [pt][k]  131584 B
  __shared__ float pscr[16][132];      // wave partials for p (8448 B)

  const int tid = threadIdx.x;
  const int lane = tid & 63;
  const int w = __builtin_amdgcn_readfirstlane(tid >> 6);       // wave id 0..15
  const int c0 = w * 16;                                        // 16-col group
  const int p0 = blockIdx.x * 128;
  const int pA = p0 + lane;            // point A
  const int pB = p0 + 64 + lane;       // point B

  // ---- layer 1: dot = z @ Win (k ascending: x,y,t), then + b_in  [bit-exact]
  {
    float xa = x[pA], ya = y[pA], ta = t[pA];
    float xb = x[pB], yb = y[pB], tb = t[pB];
    unsigned ma = 0, mb = 0;
#pragma unroll
    for (int e = 0; e < 16; ++e) {
      int c = c0 + e;                  // uniform -> Win reads are scalar
      float w0 = Win[c], w1 = Win[256 + c], w2 = Win[512 + c], bb = b_in[c];
      float da = fmaf(xa, w0, 0.f);
      da = fmaf(ya, w1, da);
      da = fmaf(ta, w2, da);
      float aa = da + bb;
      bool posa = aa > 0.f;
      hT[lane * SH + c] = posa ? aa : 0.f;
      ma |= (posa ? 1u : 0u) << e;
      float db = fmaf(xb, w0, 0.f);
      db = fmaf(yb, w1, db);
      db = fmaf(tb, w2, db);
      float ab = db + bb;
      bool posb = ab > 0.f;
      hT[(64 + lane) * SH + c] = posb ? ab : 0.f;
      mb |= (posb ? 1u : 0u) << e;
    }
    *(unsigned short*)(masks + (size_t)pA * 32 + w * 2) = (unsigned short)ma;
    *(unsigned short*)(masks + (size_t)pB * 32 + w * 2) = (unsigned short)mb;
  }
  __syncthreads();

  // ---- hidden layers: single fp32 accumulator per element, k ascending, fmaf
  for (int l = 0; l < 4; ++l) {
    const float* Wl = Wh + (size_t)l * 65536 + c0;   // + uniform col offset
    float accA[16] = {};
    float accB[16] = {};
#pragma unroll 2
    for (int k = 0; k < 256; ++k) {
      float hA = hT[lane * SH + k];          // per-lane LDS, conflict-free
      float hB = hT[(64 + lane) * SH + k];
      const float* wr = Wl + k * 256;        // wave-uniform -> s_load_dwordx16
#pragma unroll
      for (int e = 0; e < 16; ++e) {
        float wv = wr[e];
        accA[e] = fmaf(hA, wv, accA[e]);
        accB[e] = fmaf(hB, wv, accB[e]);
      }
    }
    __syncthreads();                   // all hT reads done before overwrite
    unsigned ma = 0, mb = 0;
    float hnA[16], hnB[16];
#pragma unroll
    for (int e = 0; e < 16; ++e) {
      float bb = b_h[l * 256 + c0 + e];
      float aa = accA[e] + bb;
      bool posa = aa > 0.f;
      hnA[e] = posa ? aa : 0.f;
      ma |= (posa ? 1u : 0u) << e;
      float ab = accB[e] + bb;
      bool posb = ab > 0.f;
      hnB[e] = posb ? ab : 0.f;
      mb |= (posb ? 1u : 0u) << e;
    }
    *(unsigned short*)(masks + ((size_t)(l + 1) * NPTS + pA) * 32 + w * 2) =
        (unsigned short)ma;
    *(unsigned short*)(masks + ((size_t)(l + 1) * NPTS + pB) * 32 + w * 2) =
        (unsigned short)mb;
#pragma unroll
    for (int e = 0; e < 16; ++e) {
      hT[lane * SH + c0 + e] = hnA[e];
      hT[(64 + lane) * SH + c0 + e] = hnB[e];
    }
    __syncthreads();
  }

  // ---- p = h5 . Wout[:,1] + b_out[1]  (value output; order-insensitive at
  //      bf16 comparison granularity)
  {
    float sA = 0.f, sB = 0.f;
#pragma unroll
    for (int e = 0; e < 16; ++e) {
      float wv = Wout[2 * (c0 + e) + 1];
      sA = fmaf(hT[lane * SH + c0 + e], wv, sA);
      sB = fmaf(hT[(64 + lane) * SH + c0 + e], wv, sB);
    }
    pscr[w][lane] = sA;
    pscr[w][64 + lane] = sB;
  }
  __syncthreads();
  if (tid < 128) {
    float s2 = 0.f;
#pragma unroll
    for (int g = 0; g < 16; ++g) s2 += pscr[g][tid];
    out[2 * NPTS + p0 + tid] = s2 + b_out[1];
  }
}

// ---------------------------------------------------------------- prep: Wh fp32 [l][k][n] -> f16 [l][n][k]
__global__ void __launch_bounds__(256) prep_weights_kernel(
    const float* __restrict__ Wh, _Float16* __restrict__ Wt) {
  int i = blockIdx.x * 256 + threadIdx.x;   // 0..262143
  int l = i >> 16;
  int rem = i & 65535;
  int k = rem >> 8, n = rem & 255;
  Wt[(size_t)(l << 16) + n * 256 + k] = (_Float16)Wh[i];
}

// ---------------------------------------------------------------- fused tangent chain (init + 4 layers + finalize)
// Block: 256 thr = 4 waves. 32 points -> 64 rows (0..31 x-tangent, 32..63 y).
// Tile M=64 x N=256; wave wn owns 64 rows x 64 cols (acc 4x4 16x16 tiles).
// T lives in Apan (f16) across layers; W streamed in 64-k chunks to Bpan.
// mfma_f32_16x16x32_f16: A[m=lane&15][k=quad*8+j], B[k=quad*8+j][n=lane&15],
//                        D[row=quad*4+reg][col=lane&15]  (verified layouts)
__global__ void __launch_bounds__(256, 2) tangent_fused_kernel(
    const float* __restrict__ Win,
    const _Float16* __restrict__ Wt,          // [l][n][k] (pre-transposed)
    const unsigned int* __restrict__ maskDw,  // [5][NPTS][8] dwords
    const float* __restrict__ Wout, float* __restrict__ out) {
  constexpr int SA = 264;   // A row stride (halves): 256 + 8 pad
  constexpr int SB = 72;    // B row stride (halves): 64 + 8 pad
  __shared__ alignas(16) _Float16 Apan[64 * SA];    // 33792 B
  __shared__ alignas(16) _Float16 Bpan[256 * SB];   // 36864 B
  __shared__ unsigned int smask[5 * 256];           // 5120 B

  const int tid = threadIdx.x;
  const int lane = tid & 63;
  const int wn = tid >> 6;          // wave = 64-col group
  const int l15 = lane & 15, quad = lane >> 4;
  const int p0 = blockIdx.x * 32;   // 32 points per block

  // ---- stage all 5 mask layers (32 pts x 8 dw each)
#pragma unroll
  for (int i = 0; i < 5; ++i)
    smask[i * 256 + tid] = maskDw[(size_t)i * NPTS * 8 + (size_t)p0 * 8 + tid];
  __syncthreads();

  // ---- init T1 into Apan: row<32 -> x-tangent (Win row 0), row>=32 -> y (row 1)
#pragma unroll
  for (int i = 0; i < 8; ++i) {
    int g = tid + 256 * i;          // 0..2047 col-groups of 8
    int row = g >> 5, cg = g & 31;
    int c0 = cg * 8, pt = row & 31, tg = row >> 5;
    unsigned dw = smask[pt * 8 + (c0 >> 5)];
    half8_t v;
#pragma unroll
    for (int e = 0; e < 8; ++e) {
      bool m = (dw >> ((cg & 3) * 8 + e)) & 1;
      v[e] = m ? (_Float16)Win[tg * 256 + c0 + e] : (_Float16)0.f;
    }
    *(half8_t*)&Apan[row * SA + c0] = v;
  }

  // ---- 4 layers: acc = A @ W_l, gate by mask[l+1], back into Apan as f16
  for (int l = 0; l < 4; ++l) {
    const _Float16* Wl = Wt + (size_t)l * 65536;
    floatx4 acc[4][4] = {};   // [mi][nj]
    for (int kp = 0; kp < 4; ++kp) {
      __syncthreads();        // Bpan free (and Apan init/writes visible)
      // stage B chunk: 256 n-rows x 64 k halves
#pragma unroll
      for (int i = 0; i < 8; ++i) {
        int g = tid + 256 * i;      // 0..2047 half8 segs
        int row = g >> 3, seg = g & 7;
        *(half8_t*)&Bpan[row * SB + seg * 8] =
            *(const half8_t*)(Wl + (size_t)row * 256 + kp * 64 + seg * 8);
      }
      __syncthreads();
#pragma unroll
      for (int ks = 0; ks < 2; ++ks) {
        half8_t af[4], bf[4];
#pragma unroll
        for (int mi = 0; mi < 4; ++mi)
          af[mi] = *(const half8_t*)&Apan[(mi * 16 + l15) * SA + kp * 64 + ks * 32 + quad * 8];
#pragma unroll
        for (int nj = 0; nj < 4; ++nj)
          bf[nj] = *(const half8_t*)&Bpan[(wn * 64 + nj * 16 + l15) * SB + ks * 32 + quad * 8];
#pragma unroll
        for (int mi = 0; mi < 4; ++mi)
#pragma unroll
          for (int nj = 0; nj < 4; ++nj)
            acc[mi][nj] = __builtin_amdgcn_mfma_f32_16x16x32_f16(af[mi], bf[nj], acc[mi][nj], 0, 0, 0);
      }
    }
    __syncthreads();          // all Apan reads of this layer done
    // gated write-back (C layout -> A storage), f16
    const unsigned int* ml = &smask[(l + 1) * 256];
#pragma unroll
    for (int mi = 0; mi < 4; ++mi) {
#pragma unroll
      for (int r = 0; r < 4; ++r) {
        int row = mi * 16 + quad * 4 + r;
        int pt = row & 31;
#pragma unroll
        for (int nj = 0; nj < 4; ++nj) {
          int C = wn * 64 + nj * 16 + l15;
          bool m = (ml[pt * 8 + (C >> 5)] >> (C & 31)) & 1;
          Apan[row * SA + C] = m ? (_Float16)acc[mi][nj][r] : (_Float16)0.f;
        }
      }
    }
    __syncthreads();
  }

  // ---- finalize from Apan (= T5 gated): per row, dots with Wout cols
  float4 wA = *(const float4*)(Wout + lane * 8);      // (W[c][0],W[c][1],W[c+1][0],W[c+1][1])
  float4 wB = *(const float4*)(Wout + lane * 8 + 4);
  float w0[4] = {wA.x, wA.z, wB.x, wB.z};  // Wout[:,0] for cols lane*4..+3
  float w1[4] = {wA.y, wA.w, wB.y, wB.w};  // Wout[:,1]
#pragma unroll
  for (int i = 0; i < 16; ++i) {
    int row = wn * 16 + i;
    half4_t hv = *(const half4_t*)&Apan[row * SA + lane * 4];
    float s0 = 0.f, s1 = 0.f;
#pragma unroll
    for (int e = 0; e < 4; ++e) {
      float fv = (float)hv[e];
      s0 = fmaf(fv, w0[e], s0);
      s1 = fmaf(fv, w1[e], s1);
    }
#pragma unroll
    for (int off = 1; off < 64; off <<= 1) {
      s0 += __shfl_xor(s0, off);
      s1 += __shfl_xor(s1, off);
    }
    if (lane == 0) {
      int pt = p0 + (row & 31);
      if (row < 32) {                 // x-tangent: v = -psi_x, f = p_x
        out[NPTS + pt] = -s0;
        out[3 * NPTS + pt] = s1;
      } else {                        // y-tangent: u = psi_y, g = p_y
        out[pt] = s0;
        out[4 * NPTS + pt] = s1;
      }
    }
  }
}

// ---------------------------------------------------------------- launch
extern "C" void kernel_launch(void* const* d_in, const int* in_sizes, int n_in,
                              void* d_out, int out_size, void* d_ws, size_t ws_size,
                              hipStream_t stream) {
  const float* x = (const float*)d_in[0];
  const float* y = (const float*)d_in[1];
  const float* t = (const float*)d_in[2];
  const float* Win = (const float*)d_in[3];
  const float* b_in = (const float*)d_in[4];
  const float* Wh = (const float*)d_in[5];
  const float* b_h = (const float*)d_in[6];
  const float* Wout = (const float*)d_in[7];
  const float* b_out = (const float*)d_in[8];
  float* out = (float*)d_out;

  char* ws = (char*)d_ws;
  constexpr size_t MASK_SZ = (size_t)NPTS * 32;       // 2 MB per layer
  unsigned char* masks = (unsigned char*)ws;
  _Float16* Wt = (_Float16*)(ws + 5 * MASK_SZ);

  // weight transpose/cast first (independent of fwd)
  prep_weights_kernel<<<1024, 256, 0, stream>>>(Wh, Wt);

  // fp32 np-exact forward: masks L0..L4 + p
  fwd_fused_kernel<<<NPTS / 128, 1024, 0, stream>>>(
      x, y, t, Win, b_in, Wh, b_h, Wout, b_out, masks, out);

  // fused tangent chain: init + 4 MFMA layers + finalize (u,v,f,g)
  tangent_fused_kernel<<<NPTS / 32, 256, 0, stream>>>(
      Win, Wt, (const unsigned int*)masks, Wout, out);
}